// Round 5
// baseline (932.593 us; speedup 1.0000x reference)
//
#include <hip/hip_runtime.h>

// Swin block, MI355X. B=4, H=W=192, C=256, HEADS=8, hd=32, WIN=8, SHIFT=4, HID=1024.
// I/O fp32; internal GEMMs bf16 MFMA (16x16x32), fp32 accum.
// R1: GEMM BK=64 + XOR LDS swizzle; attention: direct q/k frag loads.
// R2: fast_gelu: validated. XCD swizzle: reverted (convoy).
// R3: staging-address hoist: neutral — GEMMs are structure/latency-bound.
// R4: fused MLP: latency-starved (2 w/SIMD, 9.4M LDS conflicts on scalar smH).
// R5: FC1 transposed D=[hid][tok] -> 8B smH stores (conflicts -4x), 512-thr
//     blocks -> occupancy 20->41%. 372us; 58% still latency stalls: all FC2 W2
//     loads issue after barrier 2 (compiler can't hoist globals across
//     __syncthreads) -> every quarter, all waves eat ~300cy L2 latency cold.
// R6: W2 pipeline: w2f (nj=0, 8 frags) prefetched at quarter top — barrier 1's
//     vmcnt(0) drain forces completion under FC1's 64 MFMAs; FC2 split nj0/nj1,
//     nj1's w2g issued at FC2a start, lands under nj0's 32 MFMAs (smH re-read
//     for nj1 is cheap LDS). launch_bounds(512,4) pins occupancy.

#define SHIFT_ 4

typedef __attribute__((ext_vector_type(8))) short short8;
typedef __attribute__((ext_vector_type(4))) float floatx4;

__device__ __forceinline__ unsigned short f2b(float f) {
  union { float f; unsigned int i; } c; c.f = f;
  unsigned int u = c.i;
  return (unsigned short)((u + 0x7FFFu + ((u >> 16) & 1u)) >> 16);
}

// gelu(v) ~= v - v * rcp(1 + 2^z), z = log2(e)*2*sqrt(2/pi)*(v + 0.044715 v^3)
__device__ __forceinline__ float fast_gelu(float v) {
  const float u = v * v;
  const float z = v * (2.3022082f + 0.10294326f * u);
  const float e = __builtin_amdgcn_exp2f(z);
  const float r = __builtin_amdgcn_rcpf(1.f + e);
  return v - v * r;
}

__device__ __forceinline__ void load_lds16(const void* g, void* l) {
  __builtin_amdgcn_global_load_lds((__attribute__((address_space(1))) void*)g,
                                   (__attribute__((address_space(3))) void*)l, 16, 0, 0);
}

// window-order row -> flat token index (roll by +shift; gather==scatter map)
__device__ __forceinline__ size_t tok_of_row(int row) {
  int widx = row >> 6, t = row & 63;
  int b = widx / 576; int rem = widx - b * 576;
  int wy = rem / 24, wx = rem - wy * 24;
  int ti = t >> 3, tj = t & 7;
  int gr = wy * 8 + ti + SHIFT_; if (gr >= 192) gr -= 192;
  int gc = wx * 8 + tj + SHIFT_; if (gc >= 192) gc -= 192;
  return (size_t)b * 36864 + (size_t)(gr * 192 + gc);
}

// ---- LayerNorm (one wave per token row), optional shifted-window gather ----
template<int SHUFFLE>
__global__ __launch_bounds__(256) void ln_kernel(const float* __restrict__ src,
    const float* __restrict__ gw, const float* __restrict__ bw,
    unsigned short* __restrict__ dst) {
  const int lane = threadIdx.x & 63;
  const int m = blockIdx.x * 4 + (threadIdx.x >> 6);
  const size_t soff = SHUFFLE ? tok_of_row(m) * 256 : (size_t)m * 256;
  float4 xv = *(const float4*)(src + soff + lane * 4);
  float s  = xv.x + xv.y + xv.z + xv.w;
  float s2 = xv.x * xv.x + xv.y * xv.y + xv.z * xv.z + xv.w * xv.w;
  #pragma unroll
  for (int off = 32; off > 0; off >>= 1) { s += __shfl_xor(s, off); s2 += __shfl_xor(s2, off); }
  const float mean = s * 0.00390625f;
  const float var  = s2 * 0.00390625f - mean * mean;
  const float rstd = rsqrtf(var + 1e-5f);
  float4 gv = *(const float4*)(gw + lane * 4);
  float4 bv = *(const float4*)(bw + lane * 4);
  ushort4 o;
  o.x = f2b((xv.x - mean) * rstd * gv.x + bv.x);
  o.y = f2b((xv.y - mean) * rstd * gv.y + bv.y);
  o.z = f2b((xv.z - mean) * rstd * gv.z + bv.z);
  o.w = f2b((xv.w - mean) * rstd * gv.w + bv.w);
  *(ushort4*)(dst + (size_t)m * 256 + lane * 4) = o;
}

// ---- weight transpose fp32 KxN -> bf16 NxK ----
__global__ void wconv(const float* __restrict__ W, unsigned short* __restrict__ Wt,
                      int K, int N) {
  const int idx = blockIdx.x * 256 + threadIdx.x;
  const int n = idx / K, k = idx - n * K;
  Wt[idx] = f2b(W[(size_t)k * N + n]);
}

// ---- GEMM C[M,N] = A[M,K] @ Wt[N,K]^T. BK=64, XOR-8 swizzled LDS tiles.
// MODE 0: out bf16 = C + bias            (QKV)
// MODE 1: out f32  = X + C + bias, window->token scatter (proj + residual)
template<int MODE>
__global__ __launch_bounds__(256) void gemm_bt(
    const unsigned short* __restrict__ A, const unsigned short* __restrict__ Wt,
    const float* __restrict__ bias, const float* __restrict__ X,
    unsigned short* __restrict__ outb, float* __restrict__ outf,
    int Ntot, int K) {
  __shared__ unsigned short sm[16384];          // A 128x64 | B 128x64, both swizzled
  const int tid = threadIdx.x;
  const int wave = tid >> 6, lane = tid & 63;
  const int lr = lane & 15, lg = lane >> 4;
  const int wm = wave >> 1, wn = wave & 1;
  const int m0 = blockIdx.y * 128, n0 = blockIdx.x * 128;

  const unsigned short* rbase = (wave < 2) ? (A + (size_t)m0 * K)
                                           : (Wt + (size_t)n0 * K);
  unsigned short* ldsbase = &sm[wave * 4096];
  const int rc0 = (wave & 1) * 8;
  int off[8];
  #pragma unroll
  for (int t = 0; t < 8; ++t) {
    const int P = (rc0 + t) * 64 + lane;
    const int r = P >> 3, c = (P & 7) ^ (r & 7);
    off[t] = r * K + c * 8;
  }

  floatx4 acc[4][4];
  #pragma unroll
  for (int i = 0; i < 4; ++i)
    #pragma unroll
    for (int j = 0; j < 4; ++j) acc[i][j] = (floatx4)0.f;

  for (int k0 = 0; k0 < K; k0 += 64) {
    __syncthreads();
    #pragma unroll
    for (int t = 0; t < 8; ++t)
      load_lds16(rbase + (off[t] + k0), ldsbase + t * 512);
    __syncthreads();
    #pragma unroll
    for (int kk = 0; kk < 2; ++kk) {
      short8 af[4], bf[4];
      #pragma unroll
      for (int mi = 0; mi < 4; ++mi) {
        const int r = wm * 64 + mi * 16 + lr;
        af[mi] = *(const short8*)&sm[r * 64 + (((kk * 4 + lg) ^ (r & 7)) * 8)];
      }
      #pragma unroll
      for (int ni = 0; ni < 4; ++ni) {
        const int r = wn * 64 + ni * 16 + lr;
        bf[ni] = *(const short8*)&sm[8192 + r * 64 + (((kk * 4 + lg) ^ (r & 7)) * 8)];
      }
      #pragma unroll
      for (int mi = 0; mi < 4; ++mi)
        #pragma unroll
        for (int ni = 0; ni < 4; ++ni)
          acc[mi][ni] = __builtin_amdgcn_mfma_f32_16x16x32_bf16(af[mi], bf[ni], acc[mi][ni], 0, 0, 0);
    }
  }

  #pragma unroll
  for (int mi = 0; mi < 4; ++mi) {
    #pragma unroll
    for (int r = 0; r < 4; ++r) {
      const int row = m0 + wm * 64 + mi * 16 + lg * 4 + r;
      size_t obase;
      if (MODE == 1) obase = tok_of_row(row) * 256;
      else obase = (size_t)row * Ntot;
      #pragma unroll
      for (int ni = 0; ni < 4; ++ni) {
        const int col = n0 + wn * 64 + ni * 16 + lr;
        const float v = acc[mi][ni][r] + bias[col];
        if (MODE == 0) {
          outb[obase + col] = f2b(v);
        } else {
          outf[obase + col] = X[obase + col] + v;
        }
      }
    }
  }
}

// ---- fused LN2 + FC1 + GELU + FC2 + residual -------------------------------
// One block = 64 token rows, 512 threads (8 waves). Wave w owns hid cols
// w*32..+31 of each quarter (FC1) and out cols w*32..+31 (FC2).
// smA: [64 tok][256 k] bf16, 16B cells, cell' = cell ^ (tok&15).
// smH: [64 tok][256 hid] bf16, same swizzle. FC1 computes D=[hid][tok]
// (af=W1 rows, bf=A rows) -> 8B vectorized smH stores. FC2 acc in VGPRs.
// R6: W2 fragments register-pipelined across the barriers (see header).
__global__ __launch_bounds__(512, 4) void mlp_fused(
    float* xio, const float* __restrict__ gw, const float* __restrict__ bw,
    const unsigned short* __restrict__ w1, const float* __restrict__ b1,
    const unsigned short* __restrict__ w2, const float* __restrict__ b2) {
  __shared__ unsigned short smA[16384];
  __shared__ unsigned short smH[16384];
  const int tid = threadIdx.x;
  const int wave = tid >> 6, lane = tid & 63;
  const int lr = lane & 15, lg = lane >> 4;
  const int m0 = blockIdx.x * 64;

  // ---- LN2 into smA (wave w handles rows w*8..w*8+7) ----
  {
    const float4 gv = *(const float4*)(gw + lane * 4);
    const float4 bv = *(const float4*)(bw + lane * 4);
    #pragma unroll
    for (int rr = 0; rr < 8; ++rr) {
      const int row = wave * 8 + rr;
      float4 xv = *(const float4*)(xio + (size_t)(m0 + row) * 256 + lane * 4);
      float s  = xv.x + xv.y + xv.z + xv.w;
      float s2 = xv.x * xv.x + xv.y * xv.y + xv.z * xv.z + xv.w * xv.w;
      #pragma unroll
      for (int off = 32; off > 0; off >>= 1) { s += __shfl_xor(s, off); s2 += __shfl_xor(s2, off); }
      const float mean = s * 0.00390625f;
      const float var  = s2 * 0.00390625f - mean * mean;
      const float rstd = rsqrtf(var + 1e-5f);
      ushort4 o;
      o.x = f2b((xv.x - mean) * rstd * gv.x + bv.x);
      o.y = f2b((xv.y - mean) * rstd * gv.y + bv.y);
      o.z = f2b((xv.z - mean) * rstd * gv.z + bv.z);
      o.w = f2b((xv.w - mean) * rstd * gv.w + bv.w);
      // k0 = lane*4 lives in 16B cell (lane>>1), half (lane&1); swizzle by tok&15
      const int idx = row * 256 + ((((lane >> 1) ^ (row & 15))) << 3) + (lane & 1) * 4;
      *(ushort4*)&smA[idx] = o;
    }
  }
  __syncthreads();

  float b2v[2];
  #pragma unroll
  for (int nj = 0; nj < 2; ++nj) b2v[nj] = b2[wave * 32 + nj * 16 + lr];

  floatx4 acc2[4][2];
  #pragma unroll
  for (int i = 0; i < 4; ++i)
    #pragma unroll
    for (int j = 0; j < 2; ++j) acc2[i][j] = (floatx4)0.f;

  for (int q = 0; q < 4; ++q) {
    const unsigned short* w1q = w1 + (size_t)(q * 256 + wave * 32) * 256;
    const unsigned short* w2q = w2 + q * 256 + (size_t)(wave * 32) * 1024;

    // ---- prefetch W2 nj=0 fragments; barrier 1's vmcnt(0) drain forces
    //      completion under FC1's MFMAs, so FC2a starts with operands in regs.
    short8 w2f[8];
    #pragma unroll
    for (int kk = 0; kk < 8; ++kk)
      w2f[kk] = *(const short8*)(w2q + (size_t)lr * 1024 + kk * 32 + lg * 8);

    float4 b1v[2];
    #pragma unroll
    for (int hi = 0; hi < 2; ++hi)
      b1v[hi] = *(const float4*)(b1 + q * 256 + wave * 32 + hi * 16 + lg * 4);

    // ---- FC1 quarter, transposed: D[hid 32][tok 64] = W1q @ A^T ----
    floatx4 acc1[2][4];
    #pragma unroll
    for (int i = 0; i < 2; ++i)
      #pragma unroll
      for (int j = 0; j < 4; ++j) acc1[i][j] = (floatx4)0.f;

    #pragma unroll
    for (int kk = 0; kk < 8; ++kk) {
      short8 af[2], bf[4];
      #pragma unroll
      for (int hi = 0; hi < 2; ++hi)
        af[hi] = *(const short8*)(w1q + (hi * 16 + lr) * 256 + kk * 32 + lg * 8);
      #pragma unroll
      for (int ti = 0; ti < 4; ++ti) {
        const int tok = ti * 16 + lr;
        bf[ti] = *(const short8*)&smA[tok * 256 + (((kk * 4 + lg) ^ lr) << 3)];
      }
      #pragma unroll
      for (int hi = 0; hi < 2; ++hi)
        #pragma unroll
        for (int ti = 0; ti < 4; ++ti)
          acc1[hi][ti] = __builtin_amdgcn_mfma_f32_16x16x32_bf16(af[hi], bf[ti], acc1[hi][ti], 0, 0, 0);
    }

    __syncthreads();   // prior quarter's smH reads are done; w2f complete here
    // store: lane's 4 regs = hid wave*32+hi*16+lg*4+{0..3} at tok ti*16+lr
    #pragma unroll
    for (int hi = 0; hi < 2; ++hi) {
      const int cellbase = wave * 4 + hi * 2 + (lg >> 1);   // hid>>3
      #pragma unroll
      for (int ti = 0; ti < 4; ++ti) {
        const int tok = ti * 16 + lr;
        ushort4 hv;
        hv.x = f2b(fast_gelu(acc1[hi][ti][0] + b1v[hi].x));
        hv.y = f2b(fast_gelu(acc1[hi][ti][1] + b1v[hi].y));
        hv.z = f2b(fast_gelu(acc1[hi][ti][2] + b1v[hi].z));
        hv.w = f2b(fast_gelu(acc1[hi][ti][3] + b1v[hi].w));
        const int idx = tok * 256 + ((cellbase ^ lr) << 3) + (lg & 1) * 4;
        *(ushort4*)&smH[idx] = hv;
      }
    }
    __syncthreads();   // smH visible

    // ---- FC2a: nj=0 with preloaded w2f; issue nj=1 loads first so their
    //      latency hides under FC2a's 32 MFMAs.
    short8 w2g[8];
    #pragma unroll
    for (int kk = 0; kk < 8; ++kk)
      w2g[kk] = *(const short8*)(w2q + (size_t)(16 + lr) * 1024 + kk * 32 + lg * 8);

    #pragma unroll
    for (int kk = 0; kk < 8; ++kk) {
      short8 afk[4];
      #pragma unroll
      for (int mi = 0; mi < 4; ++mi) {
        const int tok = mi * 16 + lr;
        afk[mi] = *(const short8*)&smH[tok * 256 + (((kk * 4 + lg) ^ lr) << 3)];
      }
      #pragma unroll
      for (int mi = 0; mi < 4; ++mi)
        acc2[mi][0] = __builtin_amdgcn_mfma_f32_16x16x32_bf16(afk[mi], w2f[kk], acc2[mi][0], 0, 0, 0);
    }
    // ---- FC2b: nj=1 with w2g (landed during FC2a); smH re-read is cheap LDS.
    #pragma unroll
    for (int kk = 0; kk < 8; ++kk) {
      short8 afk[4];
      #pragma unroll
      for (int mi = 0; mi < 4; ++mi) {
        const int tok = mi * 16 + lr;
        afk[mi] = *(const short8*)&smH[tok * 256 + (((kk * 4 + lg) ^ lr) << 3)];
      }
      #pragma unroll
      for (int mi = 0; mi < 4; ++mi)
        acc2[mi][1] = __builtin_amdgcn_mfma_f32_16x16x32_bf16(afk[mi], w2g[kk], acc2[mi][1], 0, 0, 0);
    }
  }

  // ---- epilogue: xio += acc2 + b2 (in place) ----
  #pragma unroll
  for (int mi = 0; mi < 4; ++mi)
    #pragma unroll
    for (int r = 0; r < 4; ++r) {
      const size_t gbase = (size_t)(m0 + mi * 16 + lg * 4 + r) * 256;
      #pragma unroll
      for (int nj = 0; nj < 2; ++nj) {
        const int col = wave * 32 + nj * 16 + lr;
        xio[gbase + col] += acc2[mi][nj][r] + b2v[nj];
      }
    }
}

// ---- attention: one wave per (window, head). qkv rows are [3][8][32] packed.
__global__ __launch_bounds__(64) void attn_kernel(const unsigned short* __restrict__ qkv,
    const float* __restrict__ btab, unsigned short* __restrict__ obuf) {
  __shared__ unsigned short vts[2048];  // 32 x 64 (v^T), XOR-8 swizzled cells
  __shared__ unsigned short ps[4096];   // 64 x 64 probabilities, XOR-8 swizzled
  __shared__ float bs[225];
  const int l = threadIdx.x;
  const int win = blockIdx.x >> 3, head = blockIdx.x & 7;
  const int lr = l & 15, lg = l >> 4;
  const unsigned short* base = qkv + (size_t)(win * 64) * 768 + head * 32;

  #pragma unroll
  for (int c = 0; c < 8; ++c) {
    ushort4 vv = *(const ushort4*)(base + (size_t)l * 768 + 512 + c * 4);
    #pragma unroll
    for (int j = 0; j < 4; ++j) {
      const int d = c * 4 + j;
      const unsigned short val = j == 0 ? vv.x : j == 1 ? vv.y : j == 2 ? vv.z : vv.w;
      vts[d * 64 + (((l >> 3) ^ (d & 7)) * 8) + (l & 7)] = val;
    }
  }
  for (int i = l; i < 225; i += 64) bs[i] = btab[i * 8 + head];

  short8 af[4], bfr[4];
  #pragma unroll
  for (int mi = 0; mi < 4; ++mi)
    af[mi] = *(const short8*)(base + (size_t)(mi * 16 + lr) * 768 + lg * 8);
  #pragma unroll
  for (int ni = 0; ni < 4; ++ni)
    bfr[ni] = *(const short8*)(base + (size_t)(ni * 16 + lr) * 768 + 256 + lg * 8);

  floatx4 sa[4][4];
  #pragma unroll
  for (int mi = 0; mi < 4; ++mi)
    #pragma unroll
    for (int ni = 0; ni < 4; ++ni)
      sa[mi][ni] = __builtin_amdgcn_mfma_f32_16x16x32_bf16(af[mi], bfr[ni], (floatx4)0.f, 0, 0, 0);

  __syncthreads();

  const float scale = 0.17677669529663687f;
  #pragma unroll
  for (int mi = 0; mi < 4; ++mi) {
    #pragma unroll
    for (int r = 0; r < 4; ++r) {
      const int qi = mi * 16 + lg * 4 + r;
      const int ti = qi >> 3, tj = qi & 7;
      float vals[4];
      #pragma unroll
      for (int ni = 0; ni < 4; ++ni) {
        const int kc = ni * 16 + lr;
        const int tk = kc >> 3, tl = kc & 7;
        vals[ni] = sa[mi][ni][r] * scale + bs[(ti - tk + 7) * 15 + (tj - tl + 7)];
      }
      float mx = fmaxf(fmaxf(vals[0], vals[1]), fmaxf(vals[2], vals[3]));
      #pragma unroll
      for (int off = 1; off < 16; off <<= 1) mx = fmaxf(mx, __shfl_xor(mx, off, 16));
      float se = 0.f;
      #pragma unroll
      for (int ni = 0; ni < 4; ++ni) { vals[ni] = __expf(vals[ni] - mx); se += vals[ni]; }
      #pragma unroll
      for (int off = 1; off < 16; off <<= 1) se += __shfl_xor(se, off, 16);
      const float inv = 1.f / se;
      #pragma unroll
      for (int ni = 0; ni < 4; ++ni) {
        const int col = ni * 16 + lr;
        const int cell = col >> 3;
        ps[qi * 64 + ((cell ^ (qi & 7)) * 8) + (col & 7)] = f2b(vals[ni] * inv);
      }
    }
  }
  __syncthreads();

  floatx4 oa[4][2];
  #pragma unroll
  for (int mi = 0; mi < 4; ++mi) { oa[mi][0] = (floatx4)0.f; oa[mi][1] = (floatx4)0.f; }
  #pragma unroll
  for (int kk = 0; kk < 2; ++kk) {
    short8 pa[4], vb[2];
    #pragma unroll
    for (int mi = 0; mi < 4; ++mi) {
      const int r = mi * 16 + lr;
      pa[mi] = *(const short8*)&ps[r * 64 + (((kk * 4 + lg) ^ (r & 7)) * 8)];
    }
    #pragma unroll
    for (int nj = 0; nj < 2; ++nj) {
      const int r = nj * 16 + lr;
      vb[nj] = *(const short8*)&vts[r * 64 + (((kk * 4 + lg) ^ (r & 7)) * 8)];
    }
    #pragma unroll
    for (int mi = 0; mi < 4; ++mi)
      #pragma unroll
      for (int nj = 0; nj < 2; ++nj)
        oa[mi][nj] = __builtin_amdgcn_mfma_f32_16x16x32_bf16(pa[mi], vb[nj], oa[mi][nj], 0, 0, 0);
  }
  #pragma unroll
  for (int mi = 0; mi < 4; ++mi)
    #pragma unroll
    for (int nj = 0; nj < 2; ++nj)
      #pragma unroll
      for (int r = 0; r < 4; ++r) {
        const int row = mi * 16 + lg * 4 + r, d = nj * 16 + lr;
        obuf[(size_t)(win * 64 + row) * 256 + head * 32 + d] = f2b(oa[mi][nj][r]);
      }
}

extern "C" void kernel_launch(void* const* d_in, const int* in_sizes, int n_in,
                              void* d_out, int out_size, void* d_ws, size_t ws_size,
                              hipStream_t stream) {
  (void)in_sizes; (void)n_in; (void)out_size; (void)ws_size;
  const float* x      = (const float*)d_in[0];
  const float* n1g    = (const float*)d_in[1];
  const float* n1b    = (const float*)d_in[2];
  const float* qkv_w  = (const float*)d_in[3];
  const float* qkv_b  = (const float*)d_in[4];
  const float* btab   = (const float*)d_in[5];
  const float* proj_w = (const float*)d_in[6];
  const float* proj_b = (const float*)d_in[7];
  const float* n2g    = (const float*)d_in[8];
  const float* n2b    = (const float*)d_in[9];
  const float* fc1_w  = (const float*)d_in[10];
  const float* fc1_b  = (const float*)d_in[11];
  const float* fc2_w  = (const float*)d_in[12];
  const float* fc2_b  = (const float*)d_in[13];
  float* out = (float*)d_out;

  char* wsb = (char*)d_ws;
  unsigned short* wqkv  = (unsigned short*)(wsb);
  unsigned short* wproj = (unsigned short*)(wsb + 393216);
  unsigned short* wfc1  = (unsigned short*)(wsb + 524288);
  unsigned short* wfc2  = (unsigned short*)(wsb + 1048576);
  unsigned short* hbuf  = (unsigned short*)(wsb + 1572864);    // 75.5 MB
  unsigned short* big   = (unsigned short*)(wsb + 77070336);   // 302 MB

  wconv<<<768, 256, 0, stream>>>(qkv_w, wqkv, 256, 768);
  wconv<<<256, 256, 0, stream>>>(proj_w, wproj, 256, 256);
  wconv<<<1024, 256, 0, stream>>>(fc1_w, wfc1, 256, 1024);
  wconv<<<1024, 256, 0, stream>>>(fc2_w, wfc2, 1024, 256);

  // LN1 + roll/window gather -> hbuf (window order, bf16)
  ln_kernel<1><<<36864, 256, 0, stream>>>(x, n1g, n1b, hbuf);
  // QKV: (147456x256)@(256x768) -> big
  gemm_bt<0><<<dim3(6, 1152), 256, 0, stream>>>(hbuf, wqkv, qkv_b, nullptr, big, nullptr, 768, 256);
  // attention per (window, head): big -> hbuf (attn out, window order)
  attn_kernel<<<18432, 64, 0, stream>>>(big, btab, hbuf);
  // proj + window->token scatter + residual: -> d_out (fp32 x1)
  gemm_bt<1><<<dim3(2, 1152), 256, 0, stream>>>(hbuf, wproj, proj_b, x, nullptr, out, 256, 256);
  // fused LN2 + FC1 + GELU + FC2 + residual, in place on d_out
  mlp_fused<<<2304, 512, 0, stream>>>(out, n2g, n2b, wfc1, fc1_b, wfc2, fc2_b);
}

// Round 6
// 906.264 us; speedup vs baseline: 1.0291x; 1.0291x over previous
//
#include <hip/hip_runtime.h>

// Swin block, MI355X. B=4, H=W=192, C=256, HEADS=8, hd=32, WIN=8, SHIFT=4, HID=1024.
// I/O fp32; internal GEMMs bf16 MFMA (16x16x32), fp32 accum.
// R1: GEMM BK=64 + XOR LDS swizzle; attention: direct q/k frag loads.
// R2: fast_gelu: validated. XCD swizzle: reverted (convoy).
// R3: staging-address hoist: neutral — GEMMs are structure/latency-bound.
// R4: fused MLP: latency-starved (2 w/SIMD, 9.4M LDS conflicts on scalar smH).
// R5: FC1 transposed D=[hid][tok] -> 8B smH stores, 512-thr blocks: 372us.
// R6: W2 register pipeline REGRESSED (391us): allocator targeted 8 waves/EU
//     (64-VGPR step) though LDS caps at 4 waves/EU -> w2f prefetch + accs
//     spilled to scratch (FETCH +54MB, WRITE +80MB, VGPR stuck at 64).
// R7: pin budget: amdgpu_waves_per_eu(4,4) + flat_work_group_size(512,512)
//     -> 128-VGPR budget matching the LDS-dictated occupancy; b2v moved to
//     epilogue. Same R6 schedule, now with registers to run it.

#define SHIFT_ 4

typedef __attribute__((ext_vector_type(8))) short short8;
typedef __attribute__((ext_vector_type(4))) float floatx4;

__device__ __forceinline__ unsigned short f2b(float f) {
  union { float f; unsigned int i; } c; c.f = f;
  unsigned int u = c.i;
  return (unsigned short)((u + 0x7FFFu + ((u >> 16) & 1u)) >> 16);
}

// gelu(v) ~= v - v * rcp(1 + 2^z), z = log2(e)*2*sqrt(2/pi)*(v + 0.044715 v^3)
__device__ __forceinline__ float fast_gelu(float v) {
  const float u = v * v;
  const float z = v * (2.3022082f + 0.10294326f * u);
  const float e = __builtin_amdgcn_exp2f(z);
  const float r = __builtin_amdgcn_rcpf(1.f + e);
  return v - v * r;
}

__device__ __forceinline__ void load_lds16(const void* g, void* l) {
  __builtin_amdgcn_global_load_lds((__attribute__((address_space(1))) void*)g,
                                   (__attribute__((address_space(3))) void*)l, 16, 0, 0);
}

// window-order row -> flat token index (roll by +shift; gather==scatter map)
__device__ __forceinline__ size_t tok_of_row(int row) {
  int widx = row >> 6, t = row & 63;
  int b = widx / 576; int rem = widx - b * 576;
  int wy = rem / 24, wx = rem - wy * 24;
  int ti = t >> 3, tj = t & 7;
  int gr = wy * 8 + ti + SHIFT_; if (gr >= 192) gr -= 192;
  int gc = wx * 8 + tj + SHIFT_; if (gc >= 192) gc -= 192;
  return (size_t)b * 36864 + (size_t)(gr * 192 + gc);
}

// ---- LayerNorm (one wave per token row), optional shifted-window gather ----
template<int SHUFFLE>
__global__ __launch_bounds__(256) void ln_kernel(const float* __restrict__ src,
    const float* __restrict__ gw, const float* __restrict__ bw,
    unsigned short* __restrict__ dst) {
  const int lane = threadIdx.x & 63;
  const int m = blockIdx.x * 4 + (threadIdx.x >> 6);
  const size_t soff = SHUFFLE ? tok_of_row(m) * 256 : (size_t)m * 256;
  float4 xv = *(const float4*)(src + soff + lane * 4);
  float s  = xv.x + xv.y + xv.z + xv.w;
  float s2 = xv.x * xv.x + xv.y * xv.y + xv.z * xv.z + xv.w * xv.w;
  #pragma unroll
  for (int off = 32; off > 0; off >>= 1) { s += __shfl_xor(s, off); s2 += __shfl_xor(s2, off); }
  const float mean = s * 0.00390625f;
  const float var  = s2 * 0.00390625f - mean * mean;
  const float rstd = rsqrtf(var + 1e-5f);
  float4 gv = *(const float4*)(gw + lane * 4);
  float4 bv = *(const float4*)(bw + lane * 4);
  ushort4 o;
  o.x = f2b((xv.x - mean) * rstd * gv.x + bv.x);
  o.y = f2b((xv.y - mean) * rstd * gv.y + bv.y);
  o.z = f2b((xv.z - mean) * rstd * gv.z + bv.z);
  o.w = f2b((xv.w - mean) * rstd * gv.w + bv.w);
  *(ushort4*)(dst + (size_t)m * 256 + lane * 4) = o;
}

// ---- weight transpose fp32 KxN -> bf16 NxK ----
__global__ void wconv(const float* __restrict__ W, unsigned short* __restrict__ Wt,
                      int K, int N) {
  const int idx = blockIdx.x * 256 + threadIdx.x;
  const int n = idx / K, k = idx - n * K;
  Wt[idx] = f2b(W[(size_t)k * N + n]);
}

// ---- GEMM C[M,N] = A[M,K] @ Wt[N,K]^T. BK=64, XOR-8 swizzled LDS tiles.
// MODE 0: out bf16 = C + bias            (QKV)
// MODE 1: out f32  = X + C + bias, window->token scatter (proj + residual)
template<int MODE>
__global__ __launch_bounds__(256) void gemm_bt(
    const unsigned short* __restrict__ A, const unsigned short* __restrict__ Wt,
    const float* __restrict__ bias, const float* __restrict__ X,
    unsigned short* __restrict__ outb, float* __restrict__ outf,
    int Ntot, int K) {
  __shared__ unsigned short sm[16384];          // A 128x64 | B 128x64, both swizzled
  const int tid = threadIdx.x;
  const int wave = tid >> 6, lane = tid & 63;
  const int lr = lane & 15, lg = lane >> 4;
  const int wm = wave >> 1, wn = wave & 1;
  const int m0 = blockIdx.y * 128, n0 = blockIdx.x * 128;

  const unsigned short* rbase = (wave < 2) ? (A + (size_t)m0 * K)
                                           : (Wt + (size_t)n0 * K);
  unsigned short* ldsbase = &sm[wave * 4096];
  const int rc0 = (wave & 1) * 8;
  int off[8];
  #pragma unroll
  for (int t = 0; t < 8; ++t) {
    const int P = (rc0 + t) * 64 + lane;
    const int r = P >> 3, c = (P & 7) ^ (r & 7);
    off[t] = r * K + c * 8;
  }

  floatx4 acc[4][4];
  #pragma unroll
  for (int i = 0; i < 4; ++i)
    #pragma unroll
    for (int j = 0; j < 4; ++j) acc[i][j] = (floatx4)0.f;

  for (int k0 = 0; k0 < K; k0 += 64) {
    __syncthreads();
    #pragma unroll
    for (int t = 0; t < 8; ++t)
      load_lds16(rbase + (off[t] + k0), ldsbase + t * 512);
    __syncthreads();
    #pragma unroll
    for (int kk = 0; kk < 2; ++kk) {
      short8 af[4], bf[4];
      #pragma unroll
      for (int mi = 0; mi < 4; ++mi) {
        const int r = wm * 64 + mi * 16 + lr;
        af[mi] = *(const short8*)&sm[r * 64 + (((kk * 4 + lg) ^ (r & 7)) * 8)];
      }
      #pragma unroll
      for (int ni = 0; ni < 4; ++ni) {
        const int r = wn * 64 + ni * 16 + lr;
        bf[ni] = *(const short8*)&sm[8192 + r * 64 + (((kk * 4 + lg) ^ (r & 7)) * 8)];
      }
      #pragma unroll
      for (int mi = 0; mi < 4; ++mi)
        #pragma unroll
        for (int ni = 0; ni < 4; ++ni)
          acc[mi][ni] = __builtin_amdgcn_mfma_f32_16x16x32_bf16(af[mi], bf[ni], acc[mi][ni], 0, 0, 0);
    }
  }

  #pragma unroll
  for (int mi = 0; mi < 4; ++mi) {
    #pragma unroll
    for (int r = 0; r < 4; ++r) {
      const int row = m0 + wm * 64 + mi * 16 + lg * 4 + r;
      size_t obase;
      if (MODE == 1) obase = tok_of_row(row) * 256;
      else obase = (size_t)row * Ntot;
      #pragma unroll
      for (int ni = 0; ni < 4; ++ni) {
        const int col = n0 + wn * 64 + ni * 16 + lr;
        const float v = acc[mi][ni][r] + bias[col];
        if (MODE == 0) {
          outb[obase + col] = f2b(v);
        } else {
          outf[obase + col] = X[obase + col] + v;
        }
      }
    }
  }
}

// ---- fused LN2 + FC1 + GELU + FC2 + residual -------------------------------
// One block = 64 token rows, 512 threads (8 waves). Wave w owns hid cols
// w*32..+31 of each quarter (FC1) and out cols w*32..+31 (FC2).
// smA: [64 tok][256 k] bf16, 16B cells, cell' = cell ^ (tok&15).
// smH: [64 tok][256 hid] bf16, same swizzle. FC1 computes D=[hid][tok]
// (af=W1 rows, bf=A rows) -> 8B vectorized smH stores. FC2 acc in VGPRs.
// W2 fragments register-pipelined across the barriers (R6 schedule).
// waves_per_eu(4,4): allocator budget = 128 VGPR = the LDS-dictated occupancy.
__global__ __attribute__((amdgpu_flat_work_group_size(512, 512),
                          amdgpu_waves_per_eu(4, 4))) void mlp_fused(
    float* xio, const float* __restrict__ gw, const float* __restrict__ bw,
    const unsigned short* __restrict__ w1, const float* __restrict__ b1,
    const unsigned short* __restrict__ w2, const float* __restrict__ b2) {
  __shared__ unsigned short smA[16384];
  __shared__ unsigned short smH[16384];
  const int tid = threadIdx.x;
  const int wave = tid >> 6, lane = tid & 63;
  const int lr = lane & 15, lg = lane >> 4;
  const int m0 = blockIdx.x * 64;

  // ---- LN2 into smA (wave w handles rows w*8..w*8+7) ----
  {
    const float4 gv = *(const float4*)(gw + lane * 4);
    const float4 bv = *(const float4*)(bw + lane * 4);
    #pragma unroll
    for (int rr = 0; rr < 8; ++rr) {
      const int row = wave * 8 + rr;
      float4 xv = *(const float4*)(xio + (size_t)(m0 + row) * 256 + lane * 4);
      float s  = xv.x + xv.y + xv.z + xv.w;
      float s2 = xv.x * xv.x + xv.y * xv.y + xv.z * xv.z + xv.w * xv.w;
      #pragma unroll
      for (int off = 32; off > 0; off >>= 1) { s += __shfl_xor(s, off); s2 += __shfl_xor(s2, off); }
      const float mean = s * 0.00390625f;
      const float var  = s2 * 0.00390625f - mean * mean;
      const float rstd = rsqrtf(var + 1e-5f);
      ushort4 o;
      o.x = f2b((xv.x - mean) * rstd * gv.x + bv.x);
      o.y = f2b((xv.y - mean) * rstd * gv.y + bv.y);
      o.z = f2b((xv.z - mean) * rstd * gv.z + bv.z);
      o.w = f2b((xv.w - mean) * rstd * gv.w + bv.w);
      // k0 = lane*4 lives in 16B cell (lane>>1), half (lane&1); swizzle by tok&15
      const int idx = row * 256 + ((((lane >> 1) ^ (row & 15))) << 3) + (lane & 1) * 4;
      *(ushort4*)&smA[idx] = o;
    }
  }
  __syncthreads();

  floatx4 acc2[4][2];
  #pragma unroll
  for (int i = 0; i < 4; ++i)
    #pragma unroll
    for (int j = 0; j < 2; ++j) acc2[i][j] = (floatx4)0.f;

  for (int q = 0; q < 4; ++q) {
    const unsigned short* w1q = w1 + (size_t)(q * 256 + wave * 32) * 256;
    const unsigned short* w2q = w2 + q * 256 + (size_t)(wave * 32) * 1024;

    // ---- prefetch W2 nj=0 fragments; barrier 1's vmcnt(0) drain forces
    //      completion under FC1's MFMAs, so FC2a starts with operands in regs.
    short8 w2f[8];
    #pragma unroll
    for (int kk = 0; kk < 8; ++kk)
      w2f[kk] = *(const short8*)(w2q + (size_t)lr * 1024 + kk * 32 + lg * 8);

    float4 b1v[2];
    #pragma unroll
    for (int hi = 0; hi < 2; ++hi)
      b1v[hi] = *(const float4*)(b1 + q * 256 + wave * 32 + hi * 16 + lg * 4);

    // ---- FC1 quarter, transposed: D[hid 32][tok 64] = W1q @ A^T ----
    floatx4 acc1[2][4];
    #pragma unroll
    for (int i = 0; i < 2; ++i)
      #pragma unroll
      for (int j = 0; j < 4; ++j) acc1[i][j] = (floatx4)0.f;

    #pragma unroll
    for (int kk = 0; kk < 8; ++kk) {
      short8 af[2], bf[4];
      #pragma unroll
      for (int hi = 0; hi < 2; ++hi)
        af[hi] = *(const short8*)(w1q + (hi * 16 + lr) * 256 + kk * 32 + lg * 8);
      #pragma unroll
      for (int ti = 0; ti < 4; ++ti) {
        const int tok = ti * 16 + lr;
        bf[ti] = *(const short8*)&smA[tok * 256 + (((kk * 4 + lg) ^ lr) << 3)];
      }
      #pragma unroll
      for (int hi = 0; hi < 2; ++hi)
        #pragma unroll
        for (int ti = 0; ti < 4; ++ti)
          acc1[hi][ti] = __builtin_amdgcn_mfma_f32_16x16x32_bf16(af[hi], bf[ti], acc1[hi][ti], 0, 0, 0);
    }

    __syncthreads();   // prior quarter's smH reads are done; w2f complete here
    // store: lane's 4 regs = hid wave*32+hi*16+lg*4+{0..3} at tok ti*16+lr
    #pragma unroll
    for (int hi = 0; hi < 2; ++hi) {
      const int cellbase = wave * 4 + hi * 2 + (lg >> 1);   // hid>>3
      #pragma unroll
      for (int ti = 0; ti < 4; ++ti) {
        const int tok = ti * 16 + lr;
        ushort4 hv;
        hv.x = f2b(fast_gelu(acc1[hi][ti][0] + b1v[hi].x));
        hv.y = f2b(fast_gelu(acc1[hi][ti][1] + b1v[hi].y));
        hv.z = f2b(fast_gelu(acc1[hi][ti][2] + b1v[hi].z));
        hv.w = f2b(fast_gelu(acc1[hi][ti][3] + b1v[hi].w));
        const int idx = tok * 256 + ((cellbase ^ lr) << 3) + (lg & 1) * 4;
        *(ushort4*)&smH[idx] = hv;
      }
    }
    __syncthreads();   // smH visible

    // ---- FC2a: nj=0 with preloaded w2f; issue nj=1 loads first so their
    //      latency hides under FC2a's 32 MFMAs.
    short8 w2g[8];
    #pragma unroll
    for (int kk = 0; kk < 8; ++kk)
      w2g[kk] = *(const short8*)(w2q + (size_t)(16 + lr) * 1024 + kk * 32 + lg * 8);

    #pragma unroll
    for (int kk = 0; kk < 8; ++kk) {
      short8 afk[4];
      #pragma unroll
      for (int mi = 0; mi < 4; ++mi) {
        const int tok = mi * 16 + lr;
        afk[mi] = *(const short8*)&smH[tok * 256 + (((kk * 4 + lg) ^ lr) << 3)];
      }
      #pragma unroll
      for (int mi = 0; mi < 4; ++mi)
        acc2[mi][0] = __builtin_amdgcn_mfma_f32_16x16x32_bf16(afk[mi], w2f[kk], acc2[mi][0], 0, 0, 0);
    }
    // ---- FC2b: nj=1 with w2g (landed during FC2a); smH re-read is cheap LDS.
    #pragma unroll
    for (int kk = 0; kk < 8; ++kk) {
      short8 afk[4];
      #pragma unroll
      for (int mi = 0; mi < 4; ++mi) {
        const int tok = mi * 16 + lr;
        afk[mi] = *(const short8*)&smH[tok * 256 + (((kk * 4 + lg) ^ lr) << 3)];
      }
      #pragma unroll
      for (int mi = 0; mi < 4; ++mi)
        acc2[mi][1] = __builtin_amdgcn_mfma_f32_16x16x32_bf16(afk[mi], w2g[kk], acc2[mi][1], 0, 0, 0);
    }
  }

  // ---- epilogue: xio += acc2 + b2 (in place); b2 loaded here, not held ----
  float b2v[2];
  #pragma unroll
  for (int nj = 0; nj < 2; ++nj) b2v[nj] = b2[wave * 32 + nj * 16 + lr];
  #pragma unroll
  for (int mi = 0; mi < 4; ++mi)
    #pragma unroll
    for (int r = 0; r < 4; ++r) {
      const size_t gbase = (size_t)(m0 + mi * 16 + lg * 4 + r) * 256;
      #pragma unroll
      for (int nj = 0; nj < 2; ++nj) {
        const int col = wave * 32 + nj * 16 + lr;
        xio[gbase + col] += acc2[mi][nj][r] + b2v[nj];
      }
    }
}

// ---- attention: one wave per (window, head). qkv rows are [3][8][32] packed.
__global__ __launch_bounds__(64) void attn_kernel(const unsigned short* __restrict__ qkv,
    const float* __restrict__ btab, unsigned short* __restrict__ obuf) {
  __shared__ unsigned short vts[2048];  // 32 x 64 (v^T), XOR-8 swizzled cells
  __shared__ unsigned short ps[4096];   // 64 x 64 probabilities, XOR-8 swizzled
  __shared__ float bs[225];
  const int l = threadIdx.x;
  const int win = blockIdx.x >> 3, head = blockIdx.x & 7;
  const int lr = l & 15, lg = l >> 4;
  const unsigned short* base = qkv + (size_t)(win * 64) * 768 + head * 32;

  #pragma unroll
  for (int c = 0; c < 8; ++c) {
    ushort4 vv = *(const ushort4*)(base + (size_t)l * 768 + 512 + c * 4);
    #pragma unroll
    for (int j = 0; j < 4; ++j) {
      const int d = c * 4 + j;
      const unsigned short val = j == 0 ? vv.x : j == 1 ? vv.y : j == 2 ? vv.z : vv.w;
      vts[d * 64 + (((l >> 3) ^ (d & 7)) * 8) + (l & 7)] = val;
    }
  }
  for (int i = l; i < 225; i += 64) bs[i] = btab[i * 8 + head];

  short8 af[4], bfr[4];
  #pragma unroll
  for (int mi = 0; mi < 4; ++mi)
    af[mi] = *(const short8*)(base + (size_t)(mi * 16 + lr) * 768 + lg * 8);
  #pragma unroll
  for (int ni = 0; ni < 4; ++ni)
    bfr[ni] = *(const short8*)(base + (size_t)(ni * 16 + lr) * 768 + 256 + lg * 8);

  floatx4 sa[4][4];
  #pragma unroll
  for (int mi = 0; mi < 4; ++mi)
    #pragma unroll
    for (int ni = 0; ni < 4; ++ni)
      sa[mi][ni] = __builtin_amdgcn_mfma_f32_16x16x32_bf16(af[mi], bfr[ni], (floatx4)0.f, 0, 0, 0);

  __syncthreads();

  const float scale = 0.17677669529663687f;
  #pragma unroll
  for (int mi = 0; mi < 4; ++mi) {
    #pragma unroll
    for (int r = 0; r < 4; ++r) {
      const int qi = mi * 16 + lg * 4 + r;
      const int ti = qi >> 3, tj = qi & 7;
      float vals[4];
      #pragma unroll
      for (int ni = 0; ni < 4; ++ni) {
        const int kc = ni * 16 + lr;
        const int tk = kc >> 3, tl = kc & 7;
        vals[ni] = sa[mi][ni][r] * scale + bs[(ti - tk + 7) * 15 + (tj - tl + 7)];
      }
      float mx = fmaxf(fmaxf(vals[0], vals[1]), fmaxf(vals[2], vals[3]));
      #pragma unroll
      for (int off = 1; off < 16; off <<= 1) mx = fmaxf(mx, __shfl_xor(mx, off, 16));
      float se = 0.f;
      #pragma unroll
      for (int ni = 0; ni < 4; ++ni) { vals[ni] = __expf(vals[ni] - mx); se += vals[ni]; }
      #pragma unroll
      for (int off = 1; off < 16; off <<= 1) se += __shfl_xor(se, off, 16);
      const float inv = 1.f / se;
      #pragma unroll
      for (int ni = 0; ni < 4; ++ni) {
        const int col = ni * 16 + lr;
        const int cell = col >> 3;
        ps[qi * 64 + ((cell ^ (qi & 7)) * 8) + (col & 7)] = f2b(vals[ni] * inv);
      }
    }
  }
  __syncthreads();

  floatx4 oa[4][2];
  #pragma unroll
  for (int mi = 0; mi < 4; ++mi) { oa[mi][0] = (floatx4)0.f; oa[mi][1] = (floatx4)0.f; }
  #pragma unroll
  for (int kk = 0; kk < 2; ++kk) {
    short8 pa[4], vb[2];
    #pragma unroll
    for (int mi = 0; mi < 4; ++mi) {
      const int r = mi * 16 + lr;
      pa[mi] = *(const short8*)&ps[r * 64 + (((kk * 4 + lg) ^ (r & 7)) * 8)];
    }
    #pragma unroll
    for (int nj = 0; nj < 2; ++nj) {
      const int r = nj * 16 + lr;
      vb[nj] = *(const short8*)&vts[r * 64 + (((kk * 4 + lg) ^ (r & 7)) * 8)];
    }
    #pragma unroll
    for (int mi = 0; mi < 4; ++mi)
      #pragma unroll
      for (int nj = 0; nj < 2; ++nj)
        oa[mi][nj] = __builtin_amdgcn_mfma_f32_16x16x32_bf16(pa[mi], vb[nj], oa[mi][nj], 0, 0, 0);
  }
  #pragma unroll
  for (int mi = 0; mi < 4; ++mi)
    #pragma unroll
    for (int nj = 0; nj < 2; ++nj)
      #pragma unroll
      for (int r = 0; r < 4; ++r) {
        const int row = mi * 16 + lg * 4 + r, d = nj * 16 + lr;
        obuf[(size_t)(win * 64 + row) * 256 + head * 32 + d] = f2b(oa[mi][nj][r]);
      }
}

extern "C" void kernel_launch(void* const* d_in, const int* in_sizes, int n_in,
                              void* d_out, int out_size, void* d_ws, size_t ws_size,
                              hipStream_t stream) {
  (void)in_sizes; (void)n_in; (void)out_size; (void)ws_size;
  const float* x      = (const float*)d_in[0];
  const float* n1g    = (const float*)d_in[1];
  const float* n1b    = (const float*)d_in[2];
  const float* qkv_w  = (const float*)d_in[3];
  const float* qkv_b  = (const float*)d_in[4];
  const float* btab   = (const float*)d_in[5];
  const float* proj_w = (const float*)d_in[6];
  const float* proj_b = (const float*)d_in[7];
  const float* n2g    = (const float*)d_in[8];
  const float* n2b    = (const float*)d_in[9];
  const float* fc1_w  = (const float*)d_in[10];
  const float* fc1_b  = (const float*)d_in[11];
  const float* fc2_w  = (const float*)d_in[12];
  const float* fc2_b  = (const float*)d_in[13];
  float* out = (float*)d_out;

  char* wsb = (char*)d_ws;
  unsigned short* wqkv  = (unsigned short*)(wsb);
  unsigned short* wproj = (unsigned short*)(wsb + 393216);
  unsigned short* wfc1  = (unsigned short*)(wsb + 524288);
  unsigned short* wfc2  = (unsigned short*)(wsb + 1048576);
  unsigned short* hbuf  = (unsigned short*)(wsb + 1572864);    // 75.5 MB
  unsigned short* big   = (unsigned short*)(wsb + 77070336);   // 302 MB

  wconv<<<768, 256, 0, stream>>>(qkv_w, wqkv, 256, 768);
  wconv<<<256, 256, 0, stream>>>(proj_w, wproj, 256, 256);
  wconv<<<1024, 256, 0, stream>>>(fc1_w, wfc1, 256, 1024);
  wconv<<<1024, 256, 0, stream>>>(fc2_w, wfc2, 1024, 256);

  // LN1 + roll/window gather -> hbuf (window order, bf16)
  ln_kernel<1><<<36864, 256, 0, stream>>>(x, n1g, n1b, hbuf);
  // QKV: (147456x256)@(256x768) -> big
  gemm_bt<0><<<dim3(6, 1152), 256, 0, stream>>>(hbuf, wqkv, qkv_b, nullptr, big, nullptr, 768, 256);
  // attention per (window, head): big -> hbuf (attn out, window order)
  attn_kernel<<<18432, 64, 0, stream>>>(big, btab, hbuf);
  // proj + window->token scatter + residual: -> d_out (fp32 x1)
  gemm_bt<1><<<dim3(2, 1152), 256, 0, stream>>>(hbuf, wproj, proj_b, x, nullptr, out, 256, 256);
  // fused LN2 + FC1 + GELU + FC2 + residual, in place on d_out
  mlp_fused<<<2304, 512, 0, stream>>>(out, n2g, n2b, wfc1, fc1_b, wfc2, fc2_b);
}